// Round 6
// baseline (1336.781 us; speedup 1.0000x reference)
//
#include <hip/hip_runtime.h>
#include <hip/hip_bf16.h>
#include <cstdint>
#include <cstddef>

// MultiGateMixExperts: barrier-free fragment-streaming fp16 MFMA GEMMs, R6.
// 32x32x16 MFMA, frag-major layout: frag(tile32 t, kchunk16 c) = 1KB at
// ((t*64 + c)*64 + lane)*16B; lane l holds M[row=t*32+(l&31)][k=c*16+(l>>5)*8..+7].
// K-loop: depth-4 software pipeline, 4 loads + 4 MFMAs per chunk interleaved
// -> ~16 outstanding loads/wave, steady-state vmcnt~12 (AITER pattern), no LDS
// staging, no __syncthreads.
// h1 = sigmoid(x@W1[e]+b1); h2 = relu(h1@W2[e]+b2);
// f = (h2@W2[e]+b2).Wo[e] fused into stage-3 epilogue (atomicAdd over n-blocks)
// out_i = softmax(x@Wg_i+bg_i) . (f+bo)

using half8    = __attribute__((ext_vector_type(8))) _Float16;
using floatx16 = __attribute__((ext_vector_type(16))) float;

// ---------------------------------------------------------------- GEMM ------
// ACT: 0=sigmoid, 1=relu (writes C in frag layout), 2=f-fused (no C store).
// Block 128x128, 4 waves (2x2), wave tile 64x64 = 2x2 of 32x32.
template<int ACT>
__global__ __launch_bounds__(256, 2)
void gemm_kernel(const _Float16* __restrict__ A, const _Float16* __restrict__ Bt,
                 const float* __restrict__ bias, _Float16* __restrict__ C,
                 size_t a_estride,
                 const float* __restrict__ Wo, float* __restrict__ f, int e0)
{
    __shared__ _Float16 lt[4][64 * 72];   // per-wave epilogue repack tile

    const int tid  = threadIdx.x;
    const int lane = tid & 63;
    const int w    = tid >> 6;      // wave 0..3
    const int wm   = w & 1;
    const int wn   = w >> 1;

    // --- XCD-aware windowed remap (gridDim = {8, 64, g}) ---
    const int g    = gridDim.z;
    const int flat = blockIdx.x + (blockIdx.y << 3) + (blockIdx.z << 9);
    const int xcd  = flat & 7;
    int s = flat >> 3;
    int le, mb_base;
    if (g <= 8) {
        const int p = 8 / g;            // XCDs per expert
        le = xcd / p;
        mb_base = (xcd % p) * (64 / p);
    } else {                            // g == 16
        le = (xcd << 1) | (s >> 9);
        s &= 511;
        mb_base = 0;
    }
    const int nb = (s >> 2) & 7;
    const int mb = mb_base + (s >> 5) * 4 + (s & 3);
    const int m0 = mb * 128;
    const int n0 = nb * 128;

    const _Float16* Ae = A   + (size_t)le * a_estride;
    const _Float16* Be = Bt  + (size_t)le * (1024ull * 1024ull);
    const float*    be = bias + (size_t)le * 1024ull;
    _Float16*       Ce = C   + (size_t)le * (8192ull * 1024ull);

    const int mtb = (m0 >> 5) + wm * 2;   // wave's first m-tile32 (2 tiles)
    const int ntb = (n0 >> 5) + wn * 2;   // wave's first n-tile32 (2 tiles)

    // uniform bases advance 512 halves per k-chunk16; tile stride 64*512 halves
    const _Float16* bA = Ae + (size_t)mtb * 64 * 512;
    const _Float16* bB = Be + (size_t)ntb * 64 * 512;
    const uint32_t offA0 = (uint32_t)(lane * 8);
    const uint32_t offA1 = (uint32_t)(64 * 512 + lane * 8);

    floatx16 acc[2][2];
#pragma unroll
    for (int i = 0; i < 2; ++i)
#pragma unroll
        for (int j = 0; j < 2; ++j) {
            floatx16 z;
#pragma unroll
            for (int r = 0; r < 16; ++r) z[r] = 0.f;
            acc[i][j] = z;
        }

    half8 bufA[4][2], bufB[4][2];
#pragma unroll
    for (int sl = 0; sl < 4; ++sl) {               // preload chunks 0..3
        bufA[sl][0] = *(const half8*)(bA + offA0);
        bufA[sl][1] = *(const half8*)(bA + offA1);
        bufB[sl][0] = *(const half8*)(bB + offA0);
        bufB[sl][1] = *(const half8*)(bB + offA1);
        bA += 512; bB += 512;
    }

    for (int tt = 0; tt < 15; ++tt) {              // chunks 0..59, prefetch +4
#pragma unroll
        for (int sl = 0; sl < 4; ++sl) {
            acc[0][0] = __builtin_amdgcn_mfma_f32_32x32x16_f16(bufA[sl][0], bufB[sl][0], acc[0][0], 0, 0, 0);
            acc[0][1] = __builtin_amdgcn_mfma_f32_32x32x16_f16(bufA[sl][0], bufB[sl][1], acc[0][1], 0, 0, 0);
            acc[1][0] = __builtin_amdgcn_mfma_f32_32x32x16_f16(bufA[sl][1], bufB[sl][0], acc[1][0], 0, 0, 0);
            acc[1][1] = __builtin_amdgcn_mfma_f32_32x32x16_f16(bufA[sl][1], bufB[sl][1], acc[1][1], 0, 0, 0);
            bufA[sl][0] = *(const half8*)(bA + offA0);
            bufA[sl][1] = *(const half8*)(bA + offA1);
            bufB[sl][0] = *(const half8*)(bB + offA0);
            bufB[sl][1] = *(const half8*)(bB + offA1);
            bA += 512; bB += 512;
        }
    }
#pragma unroll
    for (int sl = 0; sl < 4; ++sl) {               // drain chunks 60..63
        acc[0][0] = __builtin_amdgcn_mfma_f32_32x32x16_f16(bufA[sl][0], bufB[sl][0], acc[0][0], 0, 0, 0);
        acc[0][1] = __builtin_amdgcn_mfma_f32_32x32x16_f16(bufA[sl][0], bufB[sl][1], acc[0][1], 0, 0, 0);
        acc[1][0] = __builtin_amdgcn_mfma_f32_32x32x16_f16(bufA[sl][1], bufB[sl][0], acc[1][0], 0, 0, 0);
        acc[1][1] = __builtin_amdgcn_mfma_f32_32x32x16_f16(bufA[sl][1], bufB[sl][1], acc[1][1], 0, 0, 0);
    }

    // ----- epilogue; 32x32 C/D: col=lane&31, row=(r&3)+8*(r>>2)+4*(lane>>5) --
    const int l31 = lane & 31;
    const int hh  = lane >> 5;            // 0/1
    float bj[2];
#pragma unroll
    for (int j = 0; j < 2; ++j) bj[j] = be[n0 + wn * 64 + j * 32 + l31];

    if (ACT == 2) {
        const float* we = Wo + (size_t)(e0 + le) * 1024;
        float wj[2];
#pragma unroll
        for (int j = 0; j < 2; ++j) wj[j] = we[n0 + wn * 64 + j * 32 + l31];
#pragma unroll
        for (int i = 0; i < 2; ++i) {
#pragma unroll
            for (int r = 0; r < 16; ++r) {
                float sacc = (acc[i][0][r] + bj[0]) * wj[0] + (acc[i][1][r] + bj[1]) * wj[1];
#pragma unroll
                for (int m = 1; m < 32; m <<= 1) sacc += __shfl_xor(sacc, m, 64);
                if (l31 == 0) {
                    const int row = m0 + wm * 64 + i * 32 + (r & 3) + 8 * (r >> 2) + 4 * hh;
                    atomicAdd(&f[(size_t)row * 16 + (e0 + le)], sacc);
                }
            }
        }
    } else {
        // per-wave LDS repack (no cross-wave access -> no barrier needed)
        _Float16* T = lt[w];
#pragma unroll
        for (int i = 0; i < 2; ++i)
#pragma unroll
            for (int j = 0; j < 2; ++j)
#pragma unroll
                for (int r = 0; r < 16; ++r) {
                    const int row = i * 32 + (r & 3) + 8 * (r >> 2) + 4 * hh;
                    float v = acc[i][j][r] + bj[j];
                    if (ACT == 0) v = 1.0f / (1.0f + __expf(-v));
                    else          v = fmaxf(v, 0.0f);
                    T[row * 72 + j * 32 + l31] = (_Float16)v;
                }
        // read in frag order + vectorized store
        const int kcg0 = ((n0 + wn * 64) >> 4);   // first k-chunk16 of next gemm
#pragma unroll
        for (int i = 0; i < 2; ++i) {
            const int mt = mtb + i;
#pragma unroll
            for (int c = 0; c < 4; ++c) {
                half8 v = *(const half8*)(T + (i * 32 + l31) * 72 + c * 16 + hh * 8);
                *(half8*)(Ce + ((size_t)mt * 64 + kcg0 + c) * 512 + lane * 8) = v;
            }
        }
    }
}

// --------------------------------------- cast x to fp16 frag layout ---------
// grid (16 k-blocks, 128 m-blocks), 256 threads; 64x64 tile via LDS.
__global__ __launch_bounds__(256)
void castx_kernel(const float* __restrict__ x, _Float16* __restrict__ xb)
{
    __shared__ _Float16 tile[64 * 72];   // [m-local][k-local]
    const int k0 = blockIdx.x * 64;
    const int m0 = blockIdx.y * 64;
    const int tid = threadIdx.x;
    const int col4 = (tid & 15) * 4;
    const int rb   = tid >> 4;           // 0..15
#pragma unroll
    for (int p = 0; p < 4; ++p) {
        const int row = rb + p * 16;
        float4 a = *(const float4*)(x + (size_t)(m0 + row) * 1024 + k0 + col4);
        _Float16* d = tile + row * 72 + col4;
        d[0] = (_Float16)a.x; d[1] = (_Float16)a.y; d[2] = (_Float16)a.z; d[3] = (_Float16)a.w;
    }
    __syncthreads();
    const int lane = tid & 63, w = tid >> 6;
    const int l31 = lane & 31, hh = lane >> 5;
#pragma unroll
    for (int ff = 0; ff < 2; ++ff) {
        const int fidx = w * 2 + ff;     // 0..7 = 2 m-tiles x 4 k-chunks
        const int mi = fidx >> 2, c = fidx & 3;
        half8 v = *(const half8*)(tile + (mi * 32 + l31) * 72 + c * 16 + hh * 8);
        const size_t mt = (m0 >> 5) + mi, kc = (k0 >> 4) + c;
        *(half8*)(xb + (mt * 64 + kc) * 512 + lane * 8) = v;
    }
}

// ------------------- W1/W2 [d][h] fp32 -> frag-major fp16 (n=h, k=d) --------
// grid (16 n-blocks, 16 k-blocks, 32 mats), 256 threads.
__global__ __launch_bounds__(256)
void wtr_kernel(const float* __restrict__ W1, const float* __restrict__ W2,
                _Float16* __restrict__ W1F, _Float16* __restrict__ W2F)
{
    __shared__ _Float16 tile[64 * 73];   // [k-local][n-local], pad 73
    const int z = blockIdx.z;
    const float* src = (z < 16) ? (W1 + (size_t)z * 1048576ull) : (W2 + (size_t)(z - 16) * 1048576ull);
    _Float16*    dst = (z < 16) ? (W1F + (size_t)z * 1048576ull) : (W2F + (size_t)(z - 16) * 1048576ull);
    const int n0 = blockIdx.x * 64;
    const int k0 = blockIdx.y * 64;
    const int tid = threadIdx.x;
    const int col = tid & 63;
    const int rb  = tid >> 6;            // 0..3
#pragma unroll
    for (int p = 0; p < 16; ++p) {
        const int row = rb * 16 + p;
        tile[row * 73 + col] = (_Float16)src[(size_t)(k0 + row) * 1024 + n0 + col];
    }
    __syncthreads();
    const int lane = tid & 63, w = tid >> 6;
    const int l31 = lane & 31, hh = lane >> 5;
#pragma unroll
    for (int ff = 0; ff < 2; ++ff) {
        const int fidx = w * 2 + ff;     // 0..7 = 2 n-tiles x 4 k-chunks
        const int nti = fidx >> 2, c = fidx & 3;
        half8 v;
#pragma unroll
        for (int jj = 0; jj < 8; ++jj)
            v[jj] = tile[(c * 16 + hh * 8 + jj) * 73 + nti * 32 + l31];
        const size_t nt = (n0 >> 5) + nti, kc = (k0 >> 4) + c;
        *(half8*)(dst + (nt * 64 + kc) * 512 + lane * 8) = v;
    }
}

// ---------------------------------------------------- zero f ----------------
__global__ __launch_bounds__(256)
void zerof_kernel(float* __restrict__ f)
{
    const size_t i = ((size_t)blockIdx.x * 256 + threadIdx.x) * 4;
    float4 z = {0.f, 0.f, 0.f, 0.f};
    *(float4*)(f + i) = z;
}

// ------------------ gates (fp32, full precision) + softmax + combine --------
__global__ __launch_bounds__(256)
void final_kernel(const float* __restrict__ x,
                  const float* __restrict__ Wg1, const float* __restrict__ bg1,
                  const float* __restrict__ Wg2, const float* __restrict__ bg2,
                  const float* __restrict__ f, const float* __restrict__ bo,
                  float* __restrict__ out)
{
    const int lane = threadIdx.x & 63;
    const int w    = threadIdx.x >> 6;
    const int b    = blockIdx.x * 4 + w;
    const float* xr = x + (size_t)b * 1024;
    float gp1[16], gp2[16];
#pragma unroll
    for (int e = 0; e < 16; ++e) { gp1[e] = 0.f; gp2[e] = 0.f; }
    for (int t = 0; t < 16; ++t) {
        const int d = t * 64 + lane;
        const float xv = xr[d];
        const float* w1r = Wg1 + (size_t)d * 16;
        const float* w2r = Wg2 + (size_t)d * 16;
#pragma unroll
        for (int e = 0; e < 16; ++e) { gp1[e] += xv * w1r[e]; gp2[e] += xv * w2r[e]; }
    }
#pragma unroll
    for (int e = 0; e < 16; ++e) {
#pragma unroll
        for (int m = 1; m < 64; m <<= 1) {
            gp1[e] += __shfl_xor(gp1[e], m, 64);
            gp2[e] += __shfl_xor(gp2[e], m, 64);
        }
    }
    float a1[16], a2[16], m1 = -1e30f, m2 = -1e30f;
#pragma unroll
    for (int e = 0; e < 16; ++e) {
        a1[e] = gp1[e] + bg1[e]; m1 = fmaxf(m1, a1[e]);
        a2[e] = gp2[e] + bg2[e]; m2 = fmaxf(m2, a2[e]);
    }
    float s1 = 0.f, s2 = 0.f;
#pragma unroll
    for (int e = 0; e < 16; ++e) {
        a1[e] = __expf(a1[e] - m1); s1 += a1[e];
        a2[e] = __expf(a2[e] - m2); s2 += a2[e];
    }
    float o1 = 0.f, o2 = 0.f;
    const float* fb = f + (size_t)b * 16;
#pragma unroll
    for (int e = 0; e < 16; ++e) {
        const float fe = fb[e] + bo[e];
        o1 += a1[e] * fe; o2 += a2[e] * fe;
    }
    if (lane == 0) { out[b] = o1 / s1; out[8192 + b] = o2 / s2; }
}

// ----------------------------------------------------------------------------
extern "C" void kernel_launch(void* const* d_in, const int* in_sizes, int n_in,
                              void* d_out, int out_size, void* d_ws, size_t ws_size,
                              hipStream_t stream)
{
    const float* x   = (const float*)d_in[0];
    const float* W1  = (const float*)d_in[1];
    const float* b1  = (const float*)d_in[2];
    const float* W2  = (const float*)d_in[3];
    const float* b2  = (const float*)d_in[4];
    const float* Wo  = (const float*)d_in[5];
    const float* bo  = (const float*)d_in[6];
    const float* Wg1 = (const float*)d_in[7];
    const float* bg1 = (const float*)d_in[8];
    const float* Wg2 = (const float*)d_in[9];
    const float* bg2 = (const float*)d_in[10];
    float* out = (float*)d_out;

    char* ws = (char*)d_ws;
    _Float16* xb  = (_Float16*)(ws);                         // 16 MB (frag)
    _Float16* W1F = (_Float16*)(ws + 16777216ull);           // 32 MB (frag)
    _Float16* W2F = (_Float16*)(ws + 50331648ull);           // 32 MB (frag)
    float*    f   = (float*)   (ws + 83886080ull);           // 0.5 MB
    char* hbase = ws + 84410368ull;

    int g = 1;
    const int cands[4] = {16, 8, 4, 2};
    for (int ci = 0; ci < 4; ++ci) {
        const size_t need = 84410368ull + 2ull * cands[ci] * 16777216ull;
        if (need <= ws_size) { g = cands[ci]; break; }
    }
    _Float16* h0 = (_Float16*)hbase;
    _Float16* h1 = (_Float16*)(hbase + (size_t)g * 16777216ull);

    castx_kernel<<<dim3(16, 128), 256, 0, stream>>>(x, xb);
    wtr_kernel<<<dim3(16, 16, 32), 256, 0, stream>>>(W1, W2, W1F, W2F);
    zerof_kernel<<<128, 256, 0, stream>>>(f);

    for (int e0 = 0; e0 < 16; e0 += g) {
        gemm_kernel<0><<<dim3(8, 64, g), 256, 0, stream>>>(
            xb, W1F + (size_t)e0 * 1048576ull, b1 + (size_t)e0 * 1024, h0, 0,
            nullptr, nullptr, 0);
        gemm_kernel<1><<<dim3(8, 64, g), 256, 0, stream>>>(
            h0, W2F + (size_t)e0 * 1048576ull, b2 + (size_t)e0 * 1024, h1, 8192ull * 1024ull,
            nullptr, nullptr, 0);
        gemm_kernel<2><<<dim3(8, 64, g), 256, 0, stream>>>(
            h1, W2F + (size_t)e0 * 1048576ull, b2 + (size_t)e0 * 1024, h0, 8192ull * 1024ull,
            Wo, f, e0);
    }
    final_kernel<<<2048, 256, 0, stream>>>(x, Wg1, bg1, Wg2, bg2, f, bo, out);
}